// Round 7
// baseline (29.949 us; speedup 1.0000x reference)
//
#include <hip/hip_runtime.h>
#include <hip/hip_bf16.h>

// StackedPyrHourGlassLoss — round 7.
// 2-node structure kept (measured best). Stage restructured: ONE WAVE per
// patch-block (902 blocks x 4 waves), fully wave-synchronous — no LDS, no
// __syncthreads. Validity check is a same-address broadcast load; embedding
// is shfl-broadcast from lanes 0..31 into 32 hoisted registers. Finalize
// uses float4 loads (level boundaries are float4-aligned).

constexpr int NBATCH = 2;
constexpr int EMB = 32;
constexpr int TGTC = 9;      // 1 gt + 8 affinity channels
constexpr int PZ = 5, PY = 15, PX = 15;
constexpr int P = PZ * PY * PX;   // 1125

constexpr int NBLK0 = NBATCH * 4 * 17 * 17;  // 2312
constexpr int NBLK1 = NBATCH * 4 * 9 * 9;    // 648
constexpr int NBLK2 = NBATCH * 4 * 9 * 9;    // 648
constexpr int NBLK_TOT = NBLK0 + NBLK1 + NBLK2;  // 3608  (= 4 * 902)

template <int D, int H, int W,
          int NB0, int NBH, int NBW,
          int SH, int SW,
          int DH, int DWIN,
          int OFFZ, int OFFY, int OFFX,
          int AFFB>
__device__ __forceinline__
void wave_pb(const int lbid,
             const float* __restrict__ pred,
             const int* __restrict__ tgt,
             const float* __restrict__ Wm,
             const float* __restrict__ bv,
             float* __restrict__ partials)
{
    const int lane = threadIdx.x & 63;

    int k  = lbid % NBW;
    int t1 = lbid / NBW;
    int j  = t1 % NBH;
    int t2 = t1 / NBH;
    int i  = t2 % NB0;
    int b  = t2 / NB0;

    const int HW = H * W;
    const int CH = D * HW;
    const int zc = OFFZ + i;           // z-stride is 1 at all levels
    const int yc = OFFY + j * SH;
    const int xc = OFFX + k * SW;
    const int cidx = zc * HW + yc * W + xc;

    // validity: all 64 lanes load the same addresses (hardware broadcast)
    const int c = tgt[b * TGTC * CH + cidx];
    bool allaff = true;
    #pragma unroll
    for (int ch = 0; ch < 4; ++ch)
        allaff &= (tgt[(b * TGTC + AFFB + ch) * CH + cidx] != 0);
    const bool valid = (c != 0) && allaff;

    if (!valid) {
        if (lane == 0) {
            partials[2 * lbid]     = 0.0f;
            partials[2 * lbid + 1] = 0.0f;
        }
        return;
    }

    // embedding: lane l loads emb[l&31]; broadcast to all lanes via shfl
    const float me = pred[(b * EMB + (lane & 31)) * CH + cidx];
    float ev[EMB];
    #pragma unroll
    for (int e = 0; e < EMB; ++e)
        ev[e] = __shfl(me, e);

    const int* __restrict__ gtb = tgt + b * TGTC * CH;  // gt channel

    float num = 0.0f, den = 0.0f;
    constexpr int NIT = (P + 63) / 64;   // 18
    for (int it = 0; it < NIT; ++it) {
        const int o = lane + 64 * it;
        if (o < P) {
            const int pz = o / (PY * PX);
            const int r  = o - pz * (PY * PX);
            const int py = r / PX;
            const int px = r - py * PX;

            float dot = bv[o];
            #pragma unroll
            for (int e = 0; e < EMB; ++e)
                dot = fmaf(ev[e], Wm[e * P + o], dot);
            // fast sigmoid: v_exp + v_rcp (rel err ~1e-7; threshold 4.7e-2)
            float pp = __builtin_amdgcn_rcpf(1.0f + __expf(-dot));

            const int zb = i + pz;
            const int yb = j * SH + py * DH;
            const int xb = k * SW + px * DWIN;
            bool anyz = false, anyd = false;
            #pragma unroll
            for (int wy = 0; wy < DH; ++wy) {
                #pragma unroll
                for (int wx = 0; wx < DWIN; ++wx) {
                    const int g = gtb[zb * HW + (yb + wy) * W + (xb + wx)];
                    anyz |= (g == 0);
                    anyd |= (g != c);
                }
            }
            float trg = (anyz || !anyd) ? 0.0f : 1.0f;
            if (anyz) pp = 0.0f;

            num = fmaf(pp, trg, num);
            den += pp * pp + trg * trg;
        }
    }

    // wave-level butterfly reduction (64 lanes)
    #pragma unroll
    for (int off = 32; off > 0; off >>= 1) {
        num += __shfl_xor(num, off);
        den += __shfl_xor(den, off);
    }
    if (lane == 0) {
        partials[2 * lbid]     = num;
        partials[2 * lbid + 1] = den;
    }
}

__global__ __launch_bounds__(256)
void stage_kernel(const float* __restrict__ pred0, const int* __restrict__ tgt0,
                  const float* __restrict__ W0, const float* __restrict__ b0,
                  const float* __restrict__ pred1, const int* __restrict__ tgt1,
                  const float* __restrict__ W1, const float* __restrict__ b1,
                  const float* __restrict__ pred2, const int* __restrict__ tgt2,
                  const float* __restrict__ W2, const float* __restrict__ b2,
                  float* __restrict__ partials)
{
    const int pb = blockIdx.x * 4 + (threadIdx.x >> 6);   // one wave per pb
    if (pb < NBLK0) {
        // lvl0: 8,160,160  nb=(4,17,17) stride=6 dws=4 off=(2,30,30) aff 5..8
        wave_pb<8, 160, 160, 4, 17, 17, 6, 6, 4, 4, 2, 30, 30, 5>(
            pb, pred0, tgt0, W0, b0, partials);
    } else if (pb < NBLK0 + NBLK1) {
        // lvl1: 8,80,80  nb=(4,9,9) stride=6 dws=2 off=(2,15,15) aff 1..4
        wave_pb<8, 80, 80, 4, 9, 9, 6, 6, 2, 2, 2, 15, 15, 1>(
            pb - NBLK0, pred1, tgt1, W1, b1, partials + 2 * NBLK0);
    } else {
        // lvl2: 8,40,40  nb=(4,9,9) stride=3 dws=1 off=(2,7,7) aff 1..4
        wave_pb<8, 40, 40, 4, 9, 9, 3, 3, 1, 1, 2, 7, 7, 1>(
            pb - NBLK0 - NBLK1, pred2, tgt2, W2, b2,
            partials + 2 * (NBLK0 + NBLK1));
    }
}

__global__ __launch_bounds__(256)
void finalize_kernel(const float* __restrict__ partials, float* __restrict__ out)
{
    const int tid = threadIdx.x;

    // 3608 float2 pairs = 1804 float4; level boundaries (2312, 2960) are
    // even pb indices -> every float4 is level-pure.
    constexpr int NF4 = NBLK_TOT / 2;          // 1804
    constexpr int B01 = NBLK0 / 2;             // 1156
    constexpr int B12 = (NBLK0 + NBLK1) / 2;   // 1480

    float n0 = 0.f, d0 = 0.f, n1 = 0.f, d1 = 0.f, n2 = 0.f, d2 = 0.f;
    const float4* p4 = (const float4*)partials;
    for (int p = tid; p < NF4; p += 256) {
        const float4 v = p4[p];
        if (p < B01)      { n0 += v.x + v.z; d0 += v.y + v.w; }
        else if (p < B12) { n1 += v.x + v.z; d1 += v.y + v.w; }
        else              { n2 += v.x + v.z; d2 += v.y + v.w; }
    }

    #pragma unroll
    for (int off = 32; off > 0; off >>= 1) {
        n0 += __shfl_down(n0, off);  d0 += __shfl_down(d0, off);
        n1 += __shfl_down(n1, off);  d1 += __shfl_down(d1, off);
        n2 += __shfl_down(n2, off);  d2 += __shfl_down(d2, off);
    }
    __shared__ float s[4][6];
    if ((tid & 63) == 0) {
        const int w = tid >> 6;
        s[w][0] = n0; s[w][1] = d0; s[w][2] = n1;
        s[w][3] = d1; s[w][4] = n2; s[w][5] = d2;
    }
    __syncthreads();
    if (tid == 0) {
        float acc[6];
        #pragma unroll
        for (int q = 0; q < 6; ++q)
            acc[q] = s[0][q] + s[1][q] + s[2][q] + s[3][q];
        float loss = 0.0f;
        loss += -2.0f * acc[0] / fmaxf(acc[1], 1e-6f);
        loss += -2.0f * acc[2] / fmaxf(acc[3], 1e-6f);
        loss += -2.0f * acc[4] / fmaxf(acc[5], 1e-6f);
        out[0] = loss;
    }
}

extern "C" void kernel_launch(void* const* d_in, const int* in_sizes, int n_in,
                              void* d_out, int out_size, void* d_ws, size_t ws_size,
                              hipStream_t stream)
{
    const float* pred0 = (const float*)d_in[0];
    const int*   tgt0  = (const int*)  d_in[1];
    const float* W0    = (const float*)d_in[2];
    const float* b0    = (const float*)d_in[3];
    const float* pred1 = (const float*)d_in[4];
    const int*   tgt1  = (const int*)  d_in[5];
    const float* W1    = (const float*)d_in[6];
    const float* b1    = (const float*)d_in[7];
    const float* pred2 = (const float*)d_in[8];
    const int*   tgt2  = (const int*)  d_in[9];
    const float* W2    = (const float*)d_in[10];
    const float* b2    = (const float*)d_in[11];

    float* out      = (float*)d_out;
    float* partials = (float*)d_ws;   // 3608 (num,den) pairs

    stage_kernel<<<NBLK_TOT / 4, 256, 0, stream>>>(
        pred0, tgt0, W0, b0, pred1, tgt1, W1, b1, pred2, tgt2, W2, b2,
        partials);
    finalize_kernel<<<1, 256, 0, stream>>>(partials, out);
}

// Round 9
// 25.178 us; speedup vs baseline: 1.1895x; 1.1895x over previous
//
#include <hip/hip_runtime.h>
#include <hip/hip_bf16.h>

// StackedPyrHourGlassLoss — round 9 (= round 8 resubmit; infra flake, same
// dead container as rounds 3/4 — zero measurements against this design yet).
// Lesson r7: wave-per-pb is latency-bound (3.6k waves, 18 serial outputs/lane,
// 41.7 µs). Revert to 256-thread heavy processing, and batch 8 pbs per block:
//   phase 1: 40 threads load all 8 pbs' validity words in ONE latency round,
//            invalid pbs' partials zeroed immediately (~94% of pbs).
//   phase 2: per valid pb (~0.5/block), all 256 threads run the heavy body
//            (coalesced W columns, L2-resident gt windows).
// Level boundaries (2312, 2960) divide by 8 -> each block is level-pure.
// 2-node graph kept (r5 lesson: device-scope atomics at grid scale cost ~25ns
// x gridDim serialized).

constexpr int NBATCH = 2;
constexpr int EMB = 32;
constexpr int TGTC = 9;      // 1 gt + 8 affinity channels
constexpr int PZ = 5, PY = 15, PX = 15;
constexpr int P = PZ * PY * PX;   // 1125

constexpr int NBLK0 = NBATCH * 4 * 17 * 17;  // 2312
constexpr int NBLK1 = NBATCH * 4 * 9 * 9;    // 648
constexpr int NBLK2 = NBATCH * 4 * 9 * 9;    // 648
constexpr int NBLK_TOT = NBLK0 + NBLK1 + NBLK2;  // 3608

constexpr int PBB = 8;                       // patch-blocks per workgroup
constexpr int NB0_B = NBLK0 / PBB;           // 289
constexpr int NB1_B = NBLK1 / PBB;           // 81
constexpr int NB2_B = NBLK2 / PBB;           // 81
constexpr int NBLK_B = NB0_B + NB1_B + NB2_B; // 451

template <int D, int H, int W,
          int NB0, int NBH, int NBW,
          int SH, int SW,
          int DH, int DWIN,
          int OFFZ, int OFFY, int OFFX,
          int AFFB>
__device__ __forceinline__
void block8(const int blk,                    // block index within level
            const float* __restrict__ pred,
            const int* __restrict__ tgt,
            const float* __restrict__ Wm,
            const float* __restrict__ bv,
            float* __restrict__ partials)     // level-local base
{
    const int tid = threadIdx.x;
    constexpr int HW = H * W;
    constexpr int CH = D * HW;

    __shared__ int   s_val[PBB][5];
    __shared__ int   s_meta[PBB][4];          // b, i, j, k
    __shared__ int   s_valid[PBB];
    __shared__ int   s_c[PBB];
    __shared__ float s_emb[EMB];
    __shared__ float sn[4], sd[4];

    // ---- phase 1: cooperative validity fetch (one latency round) ----
    if (tid < PBB * 5) {
        const int s = tid / 5, q = tid % 5;
        const int pb = blk * PBB + s;
        int k  = pb % NBW;
        int t1 = pb / NBW;
        int j  = t1 % NBH;
        int t2 = t1 / NBH;
        int i  = t2 % NB0;
        int b  = t2 / NB0;
        const int cidx = (OFFZ + i) * HW + (OFFY + j * SH) * W + (OFFX + k * SW);
        const int ch = (q == 0) ? 0 : (AFFB + q - 1);
        s_val[s][q] = tgt[(b * TGTC + ch) * CH + cidx];
        if (q == 0) {
            s_meta[s][0] = b; s_meta[s][1] = i;
            s_meta[s][2] = j; s_meta[s][3] = k;
        }
    }
    __syncthreads();
    if (tid < PBB) {
        const int c = s_val[tid][0];
        const bool v = (c != 0) & (s_val[tid][1] != 0) & (s_val[tid][2] != 0)
                                & (s_val[tid][3] != 0) & (s_val[tid][4] != 0);
        s_valid[tid] = v;
        s_c[tid] = c;
        if (!v) {
            const int pb = blk * PBB + tid;
            partials[2 * pb]     = 0.0f;
            partials[2 * pb + 1] = 0.0f;
        }
    }
    __syncthreads();

    // ---- phase 2: heavy processing of valid pbs (block-uniform branches) ----
    for (int s = 0; s < PBB; ++s) {
        if (!s_valid[s]) continue;            // uniform: LDS broadcast

        const int b = s_meta[s][0], i = s_meta[s][1];
        const int j = s_meta[s][2], k = s_meta[s][3];
        const int cidx = (OFFZ + i) * HW + (OFFY + j * SH) * W + (OFFX + k * SW);
        if (tid < EMB)
            s_emb[tid] = pred[(b * EMB + tid) * CH + cidx];
        __syncthreads();

        const int c = s_c[s];
        const int* __restrict__ gtb = tgt + b * TGTC * CH;

        float num = 0.0f, den = 0.0f;
        for (int o = tid; o < P; o += 256) {
            const int pz = o / (PY * PX);
            const int r  = o - pz * (PY * PX);
            const int py = r / PX;
            const int px = r - py * PX;

            float dot = bv[o];
            #pragma unroll
            for (int e = 0; e < EMB; ++e)
                dot = fmaf(s_emb[e], Wm[e * P + o], dot);
            // fast sigmoid (rel err ~1e-7; threshold 4.7e-2)
            float pp = __builtin_amdgcn_rcpf(1.0f + __expf(-dot));

            const int zb = i + pz;
            const int yb = j * SH + py * DH;
            const int xb = k * SW + px * DWIN;
            bool anyz = false, anyd = false;
            #pragma unroll
            for (int wy = 0; wy < DH; ++wy) {
                #pragma unroll
                for (int wx = 0; wx < DWIN; ++wx) {
                    const int g = gtb[zb * HW + (yb + wy) * W + (xb + wx)];
                    anyz |= (g == 0);
                    anyd |= (g != c);
                }
            }
            float trg = (anyz || !anyd) ? 0.0f : 1.0f;
            if (anyz) pp = 0.0f;

            num = fmaf(pp, trg, num);
            den += pp * pp + trg * trg;
        }

        #pragma unroll
        for (int off = 32; off > 0; off >>= 1) {
            num += __shfl_xor(num, off);
            den += __shfl_xor(den, off);
        }
        if ((tid & 63) == 0) { sn[tid >> 6] = num; sd[tid >> 6] = den; }
        __syncthreads();
        if (tid == 0) {
            const int pb = blk * PBB + s;
            partials[2 * pb]     = sn[0] + sn[1] + sn[2] + sn[3];
            partials[2 * pb + 1] = sd[0] + sd[1] + sd[2] + sd[3];
        }
        __syncthreads();   // protect s_emb/sn/sd before next slot
    }
}

__global__ __launch_bounds__(256)
void stage_kernel(const float* __restrict__ pred0, const int* __restrict__ tgt0,
                  const float* __restrict__ W0, const float* __restrict__ b0,
                  const float* __restrict__ pred1, const int* __restrict__ tgt1,
                  const float* __restrict__ W1, const float* __restrict__ b1,
                  const float* __restrict__ pred2, const int* __restrict__ tgt2,
                  const float* __restrict__ W2, const float* __restrict__ b2,
                  float* __restrict__ partials)
{
    const int gb = blockIdx.x;
    if (gb < NB0_B) {
        // lvl0: 8,160,160  nb=(4,17,17) stride=6 dws=4 off=(2,30,30) aff 5..8
        block8<8, 160, 160, 4, 17, 17, 6, 6, 4, 4, 2, 30, 30, 5>(
            gb, pred0, tgt0, W0, b0, partials);
    } else if (gb < NB0_B + NB1_B) {
        // lvl1: 8,80,80  nb=(4,9,9) stride=6 dws=2 off=(2,15,15) aff 1..4
        block8<8, 80, 80, 4, 9, 9, 6, 6, 2, 2, 2, 15, 15, 1>(
            gb - NB0_B, pred1, tgt1, W1, b1, partials + 2 * NBLK0);
    } else {
        // lvl2: 8,40,40  nb=(4,9,9) stride=3 dws=1 off=(2,7,7) aff 1..4
        block8<8, 40, 40, 4, 9, 9, 3, 3, 1, 1, 2, 7, 7, 1>(
            gb - NB0_B - NB1_B, pred2, tgt2, W2, b2,
            partials + 2 * (NBLK0 + NBLK1));
    }
}

__global__ __launch_bounds__(256)
void finalize_kernel(const float* __restrict__ partials, float* __restrict__ out)
{
    const int tid = threadIdx.x;

    // 3608 float2 pairs = 1804 float4; level boundaries (2312, 2960) are
    // even pb indices -> every float4 is level-pure.
    constexpr int NF4 = NBLK_TOT / 2;          // 1804
    constexpr int B01 = NBLK0 / 2;             // 1156
    constexpr int B12 = (NBLK0 + NBLK1) / 2;   // 1480

    float n0 = 0.f, d0 = 0.f, n1 = 0.f, d1 = 0.f, n2 = 0.f, d2 = 0.f;
    const float4* p4 = (const float4*)partials;
    for (int p = tid; p < NF4; p += 256) {
        const float4 v = p4[p];
        if (p < B01)      { n0 += v.x + v.z; d0 += v.y + v.w; }
        else if (p < B12) { n1 += v.x + v.z; d1 += v.y + v.w; }
        else              { n2 += v.x + v.z; d2 += v.y + v.w; }
    }

    #pragma unroll
    for (int off = 32; off > 0; off >>= 1) {
        n0 += __shfl_down(n0, off);  d0 += __shfl_down(d0, off);
        n1 += __shfl_down(n1, off);  d1 += __shfl_down(d1, off);
        n2 += __shfl_down(n2, off);  d2 += __shfl_down(d2, off);
    }
    __shared__ float s[4][6];
    if ((tid & 63) == 0) {
        const int w = tid >> 6;
        s[w][0] = n0; s[w][1] = d0; s[w][2] = n1;
        s[w][3] = d1; s[w][4] = n2; s[w][5] = d2;
    }
    __syncthreads();
    if (tid == 0) {
        float acc[6];
        #pragma unroll
        for (int q = 0; q < 6; ++q)
            acc[q] = s[0][q] + s[1][q] + s[2][q] + s[3][q];
        float loss = 0.0f;
        loss += -2.0f * acc[0] / fmaxf(acc[1], 1e-6f);
        loss += -2.0f * acc[2] / fmaxf(acc[3], 1e-6f);
        loss += -2.0f * acc[4] / fmaxf(acc[5], 1e-6f);
        out[0] = loss;
    }
}

extern "C" void kernel_launch(void* const* d_in, const int* in_sizes, int n_in,
                              void* d_out, int out_size, void* d_ws, size_t ws_size,
                              hipStream_t stream)
{
    const float* pred0 = (const float*)d_in[0];
    const int*   tgt0  = (const int*)  d_in[1];
    const float* W0    = (const float*)d_in[2];
    const float* b0    = (const float*)d_in[3];
    const float* pred1 = (const float*)d_in[4];
    const int*   tgt1  = (const int*)  d_in[5];
    const float* W1    = (const float*)d_in[6];
    const float* b1    = (const float*)d_in[7];
    const float* pred2 = (const float*)d_in[8];
    const int*   tgt2  = (const int*)  d_in[9];
    const float* W2    = (const float*)d_in[10];
    const float* b2    = (const float*)d_in[11];

    float* out      = (float*)d_out;
    float* partials = (float*)d_ws;   // 3608 (num,den) pairs

    stage_kernel<<<NBLK_B, 256, 0, stream>>>(
        pred0, tgt0, W0, b0, pred1, tgt1, W1, b1, pred2, tgt2, W2, b2,
        partials);
    finalize_kernel<<<1, 256, 0, stream>>>(partials, out);
}